// Round 6
// baseline (405.003 us; speedup 1.0000x reference)
//
#include <hip/hip_runtime.h>
#include <hip/hip_bf16.h>

#define N_NODES 50000
#define N_EDGES 800000
#define FEAT 128
#define CH 4
#define TM 16          // nodes per fused block (50000 = 16*3125, no tail)
#define SEG 49         // elements per scan thread: 1024*49 = 50176 >= 50000

typedef __attribute__((ext_vector_type(8))) __bf16 bf16x8;
typedef __attribute__((ext_vector_type(4))) float  f32x4;

static __device__ __forceinline__ unsigned short f2bf(float x) {
    union { float f; unsigned u; } v; v.f = x;
    unsigned r = v.u + 0x7fffu + ((v.u >> 16) & 1u);  // round-to-nearest-even
    return (unsigned short)(r >> 16);
}
static __device__ __forceinline__ unsigned packbf2(float a, float b) {
    return (unsigned)f2bf(a) | ((unsigned)f2bf(b) << 16);
}

// ---------------------------------------------------------------------------
// One prep kernel: [range A) node_state f32 -> bf16 pairs (+ deg zeroing),
// [range B) weight -> GEMM1 B-fragments, [range C) final_w -> GEMM2 B-frags.
// Fragment layout for mfma_f32_16x16x32_bf16 B: col = lane&15, k-group = lane>>4.
// ---------------------------------------------------------------------------
#define RANGE_A (N_NODES * 64)          // 3,200,000 bf16-pair words
#define RANGE_B (CH * 4 * 8 * 64)       // 8192 wfrag entries
#define RANGE_C (4 * 8 * 64)            // 2048 fwfrag entries

__global__ __launch_bounds__(256) void pack_all_kernel(
        const float* __restrict__ ns, const float* __restrict__ w,
        const float* __restrict__ fw,
        unsigned* __restrict__ nsbf, uint4* __restrict__ wf,
        uint4* __restrict__ ff, int* __restrict__ deg) {
    int idx = blockIdx.x * 256 + threadIdx.x;
    if (idx < RANGE_A) {
        const float2 x = ((const float2*)ns)[idx];
        nsbf[idx] = packbf2(x.x, x.y);
        if (idx < N_NODES) deg[idx] = 0;
        return;
    }
    idx -= RANGE_A;
    if (idx < RANGE_B) {
        const int lane = idx & 63;
        const int ct   = (idx >> 6) & 7;
        const int kt   = (idx >> 9) & 3;
        const int c    = idx >> 11;
        const int o    = ct * 16 + (lane & 15);
        const int f0   = kt * 32 + (lane >> 4) * 8;
        unsigned r[4];
        #pragma unroll
        for (int p = 0; p < 4; ++p) {
            const float lo = w[((f0 + 2 * p + 0) * FEAT + o) * CH + c];
            const float hi = w[((f0 + 2 * p + 1) * FEAT + o) * CH + c];
            r[p] = packbf2(lo, hi);
        }
        wf[idx] = make_uint4(r[0], r[1], r[2], r[3]);
        return;
    }
    idx -= RANGE_B;
    if (idx < RANGE_C) {
        const int lane = idx & 63;
        const int ct   = (idx >> 6) & 7;
        const int kt   = idx >> 9;
        const int j    = ct * 16 + (lane & 15);
        const int o0   = kt * 32 + (lane >> 4) * 8;
        unsigned r[4];
        #pragma unroll
        for (int p = 0; p < 4; ++p)
            r[p] = packbf2(fw[j * FEAT + o0 + 2 * p], fw[j * FEAT + o0 + 2 * p + 1]);
        ff[idx] = make_uint4(r[0], r[1], r[2], r[3]);
    }
}

// ---------------------------------------------------------------------------
// Counting sort by dst: histogram -> scan -> scatter(src, eid).
// ---------------------------------------------------------------------------
__global__ __launch_bounds__(256) void hist_kernel(const int* __restrict__ dst,
                                                   int* __restrict__ deg) {
    int e = blockIdx.x * 256 + threadIdx.x;
    if (e < N_EDGES) atomicAdd(&deg[dst[e]], 1);
}

// Single-block scan, thread-serial segments: t handles [t*SEG, t*SEG+SEG).
// Pass 1: segment sums; one block-scan; pass 2: write running prefix to
// offs AND cur. No cross-block coordination (same safety class as R2/R4 scan).
__global__ __launch_bounds__(1024) void scan_kernel(const int* __restrict__ deg,
                                                    int* __restrict__ offs,
                                                    int* __restrict__ cur) {
    __shared__ int wsum[16];
    const int t = threadIdx.x, lane = t & 63, wid = t >> 6;
    const int base = t * SEG;
    int s = 0;
    #pragma unroll 7
    for (int k = 0; k < SEG; ++k) {
        const int i = base + k;
        if (i < N_NODES) s += deg[i];
    }
    int incl = s;
    #pragma unroll
    for (int off = 1; off < 64; off <<= 1) {
        int u = __shfl_up(incl, off, 64);
        if (lane >= off) incl += u;
    }
    if (lane == 63) wsum[wid] = incl;
    __syncthreads();
    if (t < 16) {
        int v2 = wsum[t];
        int sc = v2;
        #pragma unroll
        for (int off = 1; off < 16; off <<= 1) {
            int u = __shfl_up(sc, off, 64);
            if (t >= off) sc += u;
        }
        wsum[t] = sc - v2;  // exclusive prefix of wave sums
    }
    __syncthreads();
    int run = wsum[wid] + incl - s;  // thread-exclusive base
    #pragma unroll 7
    for (int k = 0; k < SEG; ++k) {
        const int i = base + k;
        if (i < N_NODES) {
            offs[i] = run;
            cur[i] = run;
            run += deg[i];
        }
    }
    if (t == 0) offs[N_NODES] = N_EDGES;  // total is a known constant
}

__global__ __launch_bounds__(256) void sortscatter_kernel(
        const int* __restrict__ src, const int* __restrict__ dst,
        int* __restrict__ cur, int2* __restrict__ sorted_se) {
    int e = blockIdx.x * 256 + threadIdx.x;
    if (e >= N_EDGES) return;
    int d = dst[e];
    int pos = atomicAdd(&cur[d], 1);
    sorted_se[pos] = make_int2(src[e], e);
}

// ---------------------------------------------------------------------------
// Fused: per 16-node tile:
//   phase 1: CSR aggregate (bf16 x gathers, f32 accum) -> bf16 XOR-swizzled LDS
//   phase 2: GEMM1 via mfma_f32_16x16x32_bf16 (+bias,relu,channel-sum)
//   phase 3: h tile -> bf16 LDS (same swizzle family)
//   phase 4: GEMM2 via MFMA, + final bias, f32 out
// B-operands prepacked in global (coalesced 16B/lane, L2-resident).
// Swizzle: physical word = logical word ^ ((row&7)<<2)  [32-bit units]
// ---------------------------------------------------------------------------
#define EDGE_FMA(xu, ww) {                                          \
    const float xlo = __builtin_bit_cast(float, (xu) << 16);        \
    const float xhi = __builtin_bit_cast(float, (xu) & 0xffff0000u);\
    a0.x += xlo * ww.x; a0.y += xhi * ww.x;                         \
    a1.x += xlo * ww.y; a1.y += xhi * ww.y;                         \
    a2.x += xlo * ww.z; a2.y += xhi * ww.z;                         \
    a3.x += xlo * ww.w; a3.y += xhi * ww.w; }

__global__ __launch_bounds__(256) void fused_kernel(
        const unsigned* __restrict__ nsbf,
        const int* __restrict__ offs,
        const int2* __restrict__ sorted_se,
        const float4* __restrict__ ew4,
        const uint4* __restrict__ wfrag,
        const float* __restrict__ bias,
        const uint4* __restrict__ fwfrag,
        const float* __restrict__ fb,
        float* __restrict__ out) {
    __shared__ unsigned aggU[CH][TM][64];        // bf16 pairs, 16 KB
    __shared__ unsigned short hS[TM][FEAT];      // bf16, 4 KB
    const int t = threadIdx.x;
    const int lane = t & 63;
    const int wid = t >> 6;  // 0..3
    const int row0 = blockIdx.x * TM;

    // ---- phase 1: wave wid aggregates nodes wid*4 .. wid*4+3 ----
    for (int r = 0; r < 4; ++r) {
        const int row = wid * 4 + r;
        const int gn = row0 + row;
        float2 a0{0.f, 0.f}, a1{0.f, 0.f}, a2{0.f, 0.f}, a3{0.f, 0.f};
        {
            int e = offs[gn];
            const int end = offs[gn + 1];
            for (; e + 4 <= end; e += 4) {  // 4-deep pipeline
                const int2 p0 = sorted_se[e + 0];
                const int2 p1 = sorted_se[e + 1];
                const int2 p2 = sorted_se[e + 2];
                const int2 p3 = sorted_se[e + 3];
                const float4 w0 = ew4[p0.y];
                const float4 w1 = ew4[p1.y];
                const float4 w2 = ew4[p2.y];
                const float4 w3 = ew4[p3.y];
                const unsigned x0 = nsbf[p0.x * 64 + lane];
                const unsigned x1 = nsbf[p1.x * 64 + lane];
                const unsigned x2 = nsbf[p2.x * 64 + lane];
                const unsigned x3 = nsbf[p3.x * 64 + lane];
                EDGE_FMA(x0, w0)
                EDGE_FMA(x1, w1)
                EDGE_FMA(x2, w2)
                EDGE_FMA(x3, w3)
            }
            for (; e < end; ++e) {
                const int2 p0 = sorted_se[e];
                const float4 w0 = ew4[p0.y];
                const unsigned x0 = nsbf[p0.x * 64 + lane];
                EDGE_FMA(x0, w0)
            }
        }
        const int sw = lane ^ ((row & 7) << 2);  // swizzled word index
        aggU[0][row][sw] = packbf2(a0.x, a0.y);
        aggU[1][row][sw] = packbf2(a1.x, a1.y);
        aggU[2][row][sw] = packbf2(a2.x, a2.y);
        aggU[3][row][sw] = packbf2(a3.x, a3.y);
    }
    __syncthreads();

    // ---- phase 2: GEMM1 h = sum_c relu(agg_c @ W_c + b_c) via MFMA ----
    const int arow = lane & 15;
    const int kg4  = (lane >> 4) << 2;   // k-group in words
    const int asw  = (arow & 7) << 2;
    const int ct0  = wid * 2;            // this wave's two 16-col tiles
    const int colA = ct0 * 16 + arow;
    const int colB = colA + 16;

    f32x4 hacc0 = {0.f, 0.f, 0.f, 0.f}, hacc1 = {0.f, 0.f, 0.f, 0.f};
    #pragma unroll
    for (int c = 0; c < CH; ++c) {
        f32x4 acc0 = {0.f, 0.f, 0.f, 0.f}, acc1 = {0.f, 0.f, 0.f, 0.f};
        #pragma unroll
        for (int kt = 0; kt < 4; ++kt) {
            const uint4 au = *(const uint4*)&aggU[c][arow][(kt * 16 + kg4) ^ asw];
            const bf16x8 a  = __builtin_bit_cast(bf16x8, au);
            const bf16x8 b0 = __builtin_bit_cast(bf16x8, wfrag[((c * 4 + kt) * 8 + ct0) * 64 + lane]);
            const bf16x8 b1 = __builtin_bit_cast(bf16x8, wfrag[((c * 4 + kt) * 8 + ct0 + 1) * 64 + lane]);
            acc0 = __builtin_amdgcn_mfma_f32_16x16x32_bf16(a, b0, acc0, 0, 0, 0);
            acc1 = __builtin_amdgcn_mfma_f32_16x16x32_bf16(a, b1, acc1, 0, 0, 0);
        }
        const float bb0 = bias[colA * CH + c];
        const float bb1 = bias[colB * CH + c];
        #pragma unroll
        for (int q = 0; q < 4; ++q) {
            hacc0[q] += fmaxf(acc0[q] + bb0, 0.f);
            hacc1[q] += fmaxf(acc1[q] + bb1, 0.f);
        }
    }

    // ---- phase 3: h tile -> LDS bf16 (C/D: col=lane&15(+16ct), row=(lane>>4)*4+q) ----
    const int rrow0 = (lane >> 4) << 2;
    #pragma unroll
    for (int q = 0; q < 4; ++q) {
        const int row = rrow0 + q;
        const int s8 = (row & 7) << 3;
        hS[row][colA ^ s8] = f2bf(hacc0[q]);
        hS[row][colB ^ s8] = f2bf(hacc1[q]);
    }
    __syncthreads();

    // ---- phase 4: GEMM2 out = h @ fw^T + fb via MFMA ----
    f32x4 o0 = {0.f, 0.f, 0.f, 0.f}, o1 = {0.f, 0.f, 0.f, 0.f};
    const int asw8 = (arow & 7) << 3;
    #pragma unroll
    for (int kt = 0; kt < 4; ++kt) {
        const uint4 hu = *(const uint4*)&hS[arow][(kt * 32 + (kg4 << 1)) ^ asw8];
        const bf16x8 a  = __builtin_bit_cast(bf16x8, hu);
        const bf16x8 b0 = __builtin_bit_cast(bf16x8, fwfrag[(kt * 8 + ct0) * 64 + lane]);
        const bf16x8 b1 = __builtin_bit_cast(bf16x8, fwfrag[(kt * 8 + ct0 + 1) * 64 + lane]);
        o0 = __builtin_amdgcn_mfma_f32_16x16x32_bf16(a, b0, o0, 0, 0, 0);
        o1 = __builtin_amdgcn_mfma_f32_16x16x32_bf16(a, b1, o1, 0, 0, 0);
    }
    const float fb0 = fb[colA];
    const float fb1 = fb[colB];
    #pragma unroll
    for (int q = 0; q < 4; ++q) {
        const int gr = row0 + rrow0 + q;
        out[gr * FEAT + colA] = o0[q] + fb0;
        out[gr * FEAT + colB] = o1[q] + fb1;
    }
}

// ---------------------------------------------------------------------------
extern "C" void kernel_launch(void* const* d_in, const int* in_sizes, int n_in,
                              void* d_out, int out_size, void* d_ws, size_t ws_size,
                              hipStream_t stream) {
    const float* node_state = (const float*)d_in[0];
    const float* edge_w     = (const float*)d_in[1];
    const float* weight     = (const float*)d_in[2];
    const float* bias       = (const float*)d_in[3];
    const float* final_w    = (const float*)d_in[4];
    const float* final_b    = (const float*)d_in[5];
    const int*   src        = (const int*)d_in[6];
    const int*   dst        = (const int*)d_in[7];
    float* out = (float*)d_out;

    // Workspace layout (16B-aligned chunks):
    char* ws = (char*)d_ws;
    int*      deg       = (int*)(ws + 0);           // 200,000 B
    int*      offs      = (int*)(ws + 200064);      // 200,004 B (50001 ints)
    int*      cur       = (int*)(ws + 400128);      // 200,000 B
    int2*     sorted_se = (int2*)(ws + 600448);     // 6.4 MB
    unsigned* nsbf      = (unsigned*)(ws + 7000448);// 12.8 MB
    uint4*    wfrag     = (uint4*)(ws + 19800448);  // 131,072 B
    uint4*    fwfrag    = (uint4*)(ws + 19931520);  // 32,768 B
    // total ~19.96 MB

    const int prep_total = RANGE_A + RANGE_B + RANGE_C;
    pack_all_kernel<<<(prep_total + 255) / 256, 256, 0, stream>>>(
        node_state, weight, final_w, nsbf, wfrag, fwfrag, deg);

    hist_kernel<<<(N_EDGES + 255) / 256, 256, 0, stream>>>(dst, deg);
    scan_kernel<<<1, 1024, 0, stream>>>(deg, offs, cur);
    sortscatter_kernel<<<(N_EDGES + 255) / 256, 256, 0, stream>>>(
        src, dst, cur, sorted_se);

    fused_kernel<<<N_NODES / TM, 256, 0, stream>>>(
        nsbf, offs, sorted_se, (const float4*)edge_w,
        wfrag, bias, fwfrag, final_b, out);
}

// Round 7
// 281.911 us; speedup vs baseline: 1.4366x; 1.4366x over previous
//
#include <hip/hip_runtime.h>
#include <hip/hip_bf16.h>

#define N_NODES 50000
#define N_EDGES 800000
#define FEAT 128
#define CH 4
#define TM 16          // nodes per fused block (50000 = 16*3125, no tail)
#define NSCAN 49       // ceil(50000/1024)

typedef __attribute__((ext_vector_type(8))) __bf16 bf16x8;
typedef __attribute__((ext_vector_type(4))) float  f32x4;

static __device__ __forceinline__ unsigned short f2bf(float x) {
    union { float f; unsigned u; } v; v.f = x;
    unsigned r = v.u + 0x7fffu + ((v.u >> 16) & 1u);  // round-to-nearest-even
    return (unsigned short)(r >> 16);
}
static __device__ __forceinline__ unsigned packbf2(float a, float b) {
    return (unsigned)f2bf(a) | ((unsigned)f2bf(b) << 16);
}

// ---------------------------------------------------------------------------
// One prep kernel: [range A) node_state f32 -> bf16 pairs (+ deg zeroing),
// [range B) weight -> GEMM1 B-fragments, [range C) final_w -> GEMM2 B-frags.
// Fragment layout for mfma_f32_16x16x32_bf16 B: col = lane&15, k-group = lane>>4.
// ---------------------------------------------------------------------------
#define RANGE_A (N_NODES * 64)          // 3,200,000 bf16-pair words
#define RANGE_B (CH * 4 * 8 * 64)       // 8192 wfrag entries
#define RANGE_C (4 * 8 * 64)            // 2048 fwfrag entries

__global__ __launch_bounds__(256) void pack_all_kernel(
        const float* __restrict__ ns, const float* __restrict__ w,
        const float* __restrict__ fw,
        unsigned* __restrict__ nsbf, uint4* __restrict__ wf,
        uint4* __restrict__ ff, int* __restrict__ deg) {
    int idx = blockIdx.x * 256 + threadIdx.x;
    if (idx < RANGE_A) {
        const float2 x = ((const float2*)ns)[idx];
        nsbf[idx] = packbf2(x.x, x.y);
        if (idx < N_NODES) deg[idx] = 0;
        return;
    }
    idx -= RANGE_A;
    if (idx < RANGE_B) {
        const int lane = idx & 63;
        const int ct   = (idx >> 6) & 7;
        const int kt   = (idx >> 9) & 3;
        const int c    = idx >> 11;
        const int o    = ct * 16 + (lane & 15);
        const int f0   = kt * 32 + (lane >> 4) * 8;
        unsigned r[4];
        #pragma unroll
        for (int p = 0; p < 4; ++p) {
            const float lo = w[((f0 + 2 * p + 0) * FEAT + o) * CH + c];
            const float hi = w[((f0 + 2 * p + 1) * FEAT + o) * CH + c];
            r[p] = packbf2(lo, hi);
        }
        wf[idx] = make_uint4(r[0], r[1], r[2], r[3]);
        return;
    }
    idx -= RANGE_B;
    if (idx < RANGE_C) {
        const int lane = idx & 63;
        const int ct   = (idx >> 6) & 7;
        const int kt   = idx >> 9;
        const int j    = ct * 16 + (lane & 15);
        const int o0   = kt * 32 + (lane >> 4) * 8;
        unsigned r[4];
        #pragma unroll
        for (int p = 0; p < 4; ++p)
            r[p] = packbf2(fw[j * FEAT + o0 + 2 * p], fw[j * FEAT + o0 + 2 * p + 1]);
        ff[idx] = make_uint4(r[0], r[1], r[2], r[3]);
    }
}

// ---------------------------------------------------------------------------
// Counting sort by dst: histogram -> coalesced 2-kernel scan -> scatter.
// ---------------------------------------------------------------------------
__global__ __launch_bounds__(256) void hist_kernel(const int* __restrict__ dst,
                                                   int* __restrict__ deg) {
    int e = blockIdx.x * 256 + threadIdx.x;
    if (e < N_EDGES) atomicAdd(&deg[dst[e]], 1);
}

// scanA: block-local exclusive scan (coalesced), block totals to bsum.
__global__ __launch_bounds__(1024) void scanA_kernel(const int* __restrict__ deg,
                                                     int* __restrict__ offs,
                                                     int* __restrict__ bsum) {
    __shared__ int wsum[16];
    const int t = threadIdx.x, lane = t & 63, wid = t >> 6;
    const int i = blockIdx.x * 1024 + t;
    int v = (i < N_NODES) ? deg[i] : 0;
    int incl = v;
    #pragma unroll
    for (int off = 1; off < 64; off <<= 1) {
        int u = __shfl_up(incl, off, 64);
        if (lane >= off) incl += u;
    }
    if (lane == 63) wsum[wid] = incl;
    __syncthreads();
    if (t < 16) {
        int s = wsum[t];
        int sc = s;
        #pragma unroll
        for (int off = 1; off < 16; off <<= 1) {
            int u = __shfl_up(sc, off, 64);
            if (t >= off) sc += u;
        }
        wsum[t] = sc - s;  // exclusive prefix of wave sums
    }
    __syncthreads();
    const int excl = wsum[wid] + incl - v;  // block-local exclusive
    if (i < N_NODES) offs[i] = excl;
    if (t == 1023) bsum[blockIdx.x] = excl + v;  // block total
}

// scanB: add exclusive prefix of bsum to offs, write cur, write sentinel.
__global__ __launch_bounds__(1024) void scanB_kernel(int* __restrict__ offs,
                                                     int* __restrict__ cur,
                                                     const int* __restrict__ bsum) {
    __shared__ int pfx_s;
    const int t = threadIdx.x;
    if (t < 64) {
        int v = (t < NSCAN && t < (int)blockIdx.x) ? bsum[t] : 0;
        #pragma unroll
        for (int off = 32; off > 0; off >>= 1) v += __shfl_down(v, off, 64);
        if (t == 0) pfx_s = v;  // sum of bsum[0..blockIdx.x-1]
    }
    __syncthreads();
    const int pfx = pfx_s;
    const int i = blockIdx.x * 1024 + t;
    if (i < N_NODES) {
        const int v = offs[i] + pfx;
        offs[i] = v;
        cur[i] = v;
    }
    if (i == N_NODES) offs[N_NODES] = N_EDGES;
}

__global__ __launch_bounds__(256) void sortscatter_kernel(
        const int* __restrict__ src, const int* __restrict__ dst,
        int* __restrict__ cur, int2* __restrict__ sorted_se) {
    int e = blockIdx.x * 256 + threadIdx.x;
    if (e >= N_EDGES) return;
    int d = dst[e];
    int pos = atomicAdd(&cur[d], 1);
    sorted_se[pos] = make_int2(src[e], e);
}

// ---------------------------------------------------------------------------
// Fused: per 16-node tile:
//   phase 1: CSR aggregate (bf16 x gathers, f32 accum) -> bf16 XOR-swizzled LDS
//   phase 2: GEMM1 via mfma_f32_16x16x32_bf16 (+bias,relu,channel-sum)
//   phase 3: h tile -> bf16 LDS (same swizzle family)
//   phase 4: GEMM2 via MFMA, + final bias, f32 out
// B-operands prepacked in global (coalesced 16B/lane, L2-resident).
// Swizzle: physical word = logical word ^ ((row&7)<<2)  [32-bit units]
// ---------------------------------------------------------------------------
#define EDGE_FMA(xu, ww) {                                          \
    const float xlo = __builtin_bit_cast(float, (xu) << 16);        \
    const float xhi = __builtin_bit_cast(float, (xu) & 0xffff0000u);\
    a0.x += xlo * ww.x; a0.y += xhi * ww.x;                         \
    a1.x += xlo * ww.y; a1.y += xhi * ww.y;                         \
    a2.x += xlo * ww.z; a2.y += xhi * ww.z;                         \
    a3.x += xlo * ww.w; a3.y += xhi * ww.w; }

__global__ __launch_bounds__(256) void fused_kernel(
        const unsigned* __restrict__ nsbf,
        const int* __restrict__ offs,
        const int2* __restrict__ sorted_se,
        const float4* __restrict__ ew4,
        const uint4* __restrict__ wfrag,
        const float* __restrict__ bias,
        const uint4* __restrict__ fwfrag,
        const float* __restrict__ fb,
        float* __restrict__ out) {
    __shared__ unsigned aggU[CH][TM][64];        // bf16 pairs, 16 KB
    __shared__ unsigned short hS[TM][FEAT];      // bf16, 4 KB
    const int t = threadIdx.x;
    const int lane = t & 63;
    const int wid = t >> 6;  // 0..3
    const int row0 = blockIdx.x * TM;

    // ---- phase 1: wave wid aggregates nodes wid*4 .. wid*4+3 ----
    for (int r = 0; r < 4; ++r) {
        const int row = wid * 4 + r;
        const int gn = row0 + row;
        float2 a0{0.f, 0.f}, a1{0.f, 0.f}, a2{0.f, 0.f}, a3{0.f, 0.f};
        {
            int e = offs[gn];
            const int end = offs[gn + 1];
            for (; e + 4 <= end; e += 4) {  // 4-deep pipeline
                const int2 p0 = sorted_se[e + 0];
                const int2 p1 = sorted_se[e + 1];
                const int2 p2 = sorted_se[e + 2];
                const int2 p3 = sorted_se[e + 3];
                const float4 w0 = ew4[p0.y];
                const float4 w1 = ew4[p1.y];
                const float4 w2 = ew4[p2.y];
                const float4 w3 = ew4[p3.y];
                const unsigned x0 = nsbf[p0.x * 64 + lane];
                const unsigned x1 = nsbf[p1.x * 64 + lane];
                const unsigned x2 = nsbf[p2.x * 64 + lane];
                const unsigned x3 = nsbf[p3.x * 64 + lane];
                EDGE_FMA(x0, w0)
                EDGE_FMA(x1, w1)
                EDGE_FMA(x2, w2)
                EDGE_FMA(x3, w3)
            }
            for (; e < end; ++e) {
                const int2 p0 = sorted_se[e];
                const float4 w0 = ew4[p0.y];
                const unsigned x0 = nsbf[p0.x * 64 + lane];
                EDGE_FMA(x0, w0)
            }
        }
        const int sw = lane ^ ((row & 7) << 2);  // swizzled word index
        aggU[0][row][sw] = packbf2(a0.x, a0.y);
        aggU[1][row][sw] = packbf2(a1.x, a1.y);
        aggU[2][row][sw] = packbf2(a2.x, a2.y);
        aggU[3][row][sw] = packbf2(a3.x, a3.y);
    }
    __syncthreads();

    // ---- phase 2: GEMM1 h = sum_c relu(agg_c @ W_c + b_c) via MFMA ----
    const int arow = lane & 15;
    const int kg4  = (lane >> 4) << 2;   // k-group in words
    const int asw  = (arow & 7) << 2;
    const int ct0  = wid * 2;            // this wave's two 16-col tiles
    const int colA = ct0 * 16 + arow;
    const int colB = colA + 16;

    f32x4 hacc0 = {0.f, 0.f, 0.f, 0.f}, hacc1 = {0.f, 0.f, 0.f, 0.f};
    #pragma unroll
    for (int c = 0; c < CH; ++c) {
        f32x4 acc0 = {0.f, 0.f, 0.f, 0.f}, acc1 = {0.f, 0.f, 0.f, 0.f};
        #pragma unroll
        for (int kt = 0; kt < 4; ++kt) {
            const uint4 au = *(const uint4*)&aggU[c][arow][(kt * 16 + kg4) ^ asw];
            const bf16x8 a  = __builtin_bit_cast(bf16x8, au);
            const bf16x8 b0 = __builtin_bit_cast(bf16x8, wfrag[((c * 4 + kt) * 8 + ct0) * 64 + lane]);
            const bf16x8 b1 = __builtin_bit_cast(bf16x8, wfrag[((c * 4 + kt) * 8 + ct0 + 1) * 64 + lane]);
            acc0 = __builtin_amdgcn_mfma_f32_16x16x32_bf16(a, b0, acc0, 0, 0, 0);
            acc1 = __builtin_amdgcn_mfma_f32_16x16x32_bf16(a, b1, acc1, 0, 0, 0);
        }
        const float bb0 = bias[colA * CH + c];
        const float bb1 = bias[colB * CH + c];
        #pragma unroll
        for (int q = 0; q < 4; ++q) {
            hacc0[q] += fmaxf(acc0[q] + bb0, 0.f);
            hacc1[q] += fmaxf(acc1[q] + bb1, 0.f);
        }
    }

    // ---- phase 3: h tile -> LDS bf16 (C/D: col=lane&15(+16ct), row=(lane>>4)*4+q) ----
    const int rrow0 = (lane >> 4) << 2;
    #pragma unroll
    for (int q = 0; q < 4; ++q) {
        const int row = rrow0 + q;
        const int s8 = (row & 7) << 3;
        hS[row][colA ^ s8] = f2bf(hacc0[q]);
        hS[row][colB ^ s8] = f2bf(hacc1[q]);
    }
    __syncthreads();

    // ---- phase 4: GEMM2 out = h @ fw^T + fb via MFMA ----
    f32x4 o0 = {0.f, 0.f, 0.f, 0.f}, o1 = {0.f, 0.f, 0.f, 0.f};
    const int asw8 = (arow & 7) << 3;
    #pragma unroll
    for (int kt = 0; kt < 4; ++kt) {
        const uint4 hu = *(const uint4*)&hS[arow][(kt * 32 + (kg4 << 1)) ^ asw8];
        const bf16x8 a  = __builtin_bit_cast(bf16x8, hu);
        const bf16x8 b0 = __builtin_bit_cast(bf16x8, fwfrag[(kt * 8 + ct0) * 64 + lane]);
        const bf16x8 b1 = __builtin_bit_cast(bf16x8, fwfrag[(kt * 8 + ct0 + 1) * 64 + lane]);
        o0 = __builtin_amdgcn_mfma_f32_16x16x32_bf16(a, b0, o0, 0, 0, 0);
        o1 = __builtin_amdgcn_mfma_f32_16x16x32_bf16(a, b1, o1, 0, 0, 0);
    }
    const float fb0 = fb[colA];
    const float fb1 = fb[colB];
    #pragma unroll
    for (int q = 0; q < 4; ++q) {
        const int gr = row0 + rrow0 + q;
        out[gr * FEAT + colA] = o0[q] + fb0;
        out[gr * FEAT + colB] = o1[q] + fb1;
    }
}

// ---------------------------------------------------------------------------
extern "C" void kernel_launch(void* const* d_in, const int* in_sizes, int n_in,
                              void* d_out, int out_size, void* d_ws, size_t ws_size,
                              hipStream_t stream) {
    const float* node_state = (const float*)d_in[0];
    const float* edge_w     = (const float*)d_in[1];
    const float* weight     = (const float*)d_in[2];
    const float* bias       = (const float*)d_in[3];
    const float* final_w    = (const float*)d_in[4];
    const float* final_b    = (const float*)d_in[5];
    const int*   src        = (const int*)d_in[6];
    const int*   dst        = (const int*)d_in[7];
    float* out = (float*)d_out;

    // Workspace layout (16B-aligned chunks):
    char* ws = (char*)d_ws;
    int*      deg       = (int*)(ws + 0);           // 200,000 B
    int*      offs      = (int*)(ws + 200064);      // 200,004 B (50001 ints)
    int*      cur       = (int*)(ws + 400128);      // 200,000 B
    int*      bsum      = (int*)(ws + 600192);      // 196 B
    int2*     sorted_se = (int2*)(ws + 600448);     // 6.4 MB
    unsigned* nsbf      = (unsigned*)(ws + 7000448);// 12.8 MB
    uint4*    wfrag     = (uint4*)(ws + 19800448);  // 131,072 B
    uint4*    fwfrag    = (uint4*)(ws + 19931520);  // 32,768 B
    // total ~19.96 MB

    const int prep_total = RANGE_A + RANGE_B + RANGE_C;
    pack_all_kernel<<<(prep_total + 255) / 256, 256, 0, stream>>>(
        node_state, weight, final_w, nsbf, wfrag, fwfrag, deg);

    hist_kernel<<<(N_EDGES + 255) / 256, 256, 0, stream>>>(dst, deg);
    scanA_kernel<<<NSCAN, 1024, 0, stream>>>(deg, offs, bsum);
    scanB_kernel<<<NSCAN, 1024, 0, stream>>>(offs, cur, bsum);
    sortscatter_kernel<<<(N_EDGES + 255) / 256, 256, 0, stream>>>(
        src, dst, cur, sorted_se);

    fused_kernel<<<N_NODES / TM, 256, 0, stream>>>(
        nsbf, offs, sorted_se, (const float4*)edge_w,
        wfrag, bias, fwfrag, final_b, out);
}

// Round 8
// 252.126 us; speedup vs baseline: 1.6064x; 1.1181x over previous
//
#include <hip/hip_runtime.h>
#include <hip/hip_bf16.h>

#define N_NODES 50000
#define N_EDGES 800000
#define FEAT 128
#define CH 4
#define TM 16          // nodes per fused block (50000 = 16*3125, no tail)
#define NSCAN 49       // ceil(50000/1024)

typedef __attribute__((ext_vector_type(8))) __bf16 bf16x8;
typedef __attribute__((ext_vector_type(4))) float  f32x4;

static __device__ __forceinline__ unsigned short f2bf(float x) {
    union { float f; unsigned u; } v; v.f = x;
    unsigned r = v.u + 0x7fffu + ((v.u >> 16) & 1u);  // round-to-nearest-even
    return (unsigned short)(r >> 16);
}
static __device__ __forceinline__ unsigned packbf2(float a, float b) {
    return (unsigned)f2bf(a) | ((unsigned)f2bf(b) << 16);
}
static __device__ __forceinline__ float bfl(unsigned u) {
    return __builtin_bit_cast(float, u << 16);
}
static __device__ __forceinline__ float bfh(unsigned u) {
    return __builtin_bit_cast(float, u & 0xffff0000u);
}

// ---------------------------------------------------------------------------
// One prep kernel: [range A) node_state f32 -> bf16 pairs (+ deg zeroing),
// [range B) weight -> GEMM1 B-fragments, [range C) final_w -> GEMM2 B-frags.
// Fragment layout for mfma_f32_16x16x32_bf16 B: col = lane&15, k-group = lane>>4.
// ---------------------------------------------------------------------------
#define RANGE_A (N_NODES * 64)          // 3,200,000 bf16-pair words
#define RANGE_B (CH * 4 * 8 * 64)       // 8192 wfrag entries
#define RANGE_C (4 * 8 * 64)            // 2048 fwfrag entries

__global__ __launch_bounds__(256) void pack_all_kernel(
        const float* __restrict__ ns, const float* __restrict__ w,
        const float* __restrict__ fw,
        unsigned* __restrict__ nsbf, uint4* __restrict__ wf,
        uint4* __restrict__ ff, int* __restrict__ deg) {
    int idx = blockIdx.x * 256 + threadIdx.x;
    if (idx < RANGE_A) {
        const float2 x = ((const float2*)ns)[idx];
        nsbf[idx] = packbf2(x.x, x.y);
        if (idx < N_NODES) deg[idx] = 0;
        return;
    }
    idx -= RANGE_A;
    if (idx < RANGE_B) {
        const int lane = idx & 63;
        const int ct   = (idx >> 6) & 7;
        const int kt   = (idx >> 9) & 3;
        const int c    = idx >> 11;
        const int o    = ct * 16 + (lane & 15);
        const int f0   = kt * 32 + (lane >> 4) * 8;
        unsigned r[4];
        #pragma unroll
        for (int p = 0; p < 4; ++p) {
            const float lo = w[((f0 + 2 * p + 0) * FEAT + o) * CH + c];
            const float hi = w[((f0 + 2 * p + 1) * FEAT + o) * CH + c];
            r[p] = packbf2(lo, hi);
        }
        wf[idx] = make_uint4(r[0], r[1], r[2], r[3]);
        return;
    }
    idx -= RANGE_B;
    if (idx < RANGE_C) {
        const int lane = idx & 63;
        const int ct   = (idx >> 6) & 7;
        const int kt   = idx >> 9;
        const int j    = ct * 16 + (lane & 15);
        const int o0   = kt * 32 + (lane >> 4) * 8;
        unsigned r[4];
        #pragma unroll
        for (int p = 0; p < 4; ++p)
            r[p] = packbf2(fw[j * FEAT + o0 + 2 * p], fw[j * FEAT + o0 + 2 * p + 1]);
        ff[idx] = make_uint4(r[0], r[1], r[2], r[3]);
    }
}

// ---------------------------------------------------------------------------
// Counting sort by dst: histogram -> coalesced 2-kernel scan -> scatter.
// ---------------------------------------------------------------------------
__global__ __launch_bounds__(256) void hist_kernel(const int* __restrict__ dst,
                                                   int* __restrict__ deg) {
    int e = blockIdx.x * 256 + threadIdx.x;
    if (e < N_EDGES) atomicAdd(&deg[dst[e]], 1);
}

// scanA: block-local exclusive scan (coalesced), block totals to bsum.
__global__ __launch_bounds__(1024) void scanA_kernel(const int* __restrict__ deg,
                                                     int* __restrict__ offs,
                                                     int* __restrict__ bsum) {
    __shared__ int wsum[16];
    const int t = threadIdx.x, lane = t & 63, wid = t >> 6;
    const int i = blockIdx.x * 1024 + t;
    int v = (i < N_NODES) ? deg[i] : 0;
    int incl = v;
    #pragma unroll
    for (int off = 1; off < 64; off <<= 1) {
        int u = __shfl_up(incl, off, 64);
        if (lane >= off) incl += u;
    }
    if (lane == 63) wsum[wid] = incl;
    __syncthreads();
    if (t < 16) {
        int s = wsum[t];
        int sc = s;
        #pragma unroll
        for (int off = 1; off < 16; off <<= 1) {
            int u = __shfl_up(sc, off, 64);
            if (t >= off) sc += u;
        }
        wsum[t] = sc - s;  // exclusive prefix of wave sums
    }
    __syncthreads();
    const int excl = wsum[wid] + incl - v;  // block-local exclusive
    if (i < N_NODES) offs[i] = excl;
    if (t == 1023) bsum[blockIdx.x] = excl + v;  // block total
}

// scanB: add exclusive prefix of bsum to offs, write sentinel.
__global__ __launch_bounds__(1024) void scanB_kernel(int* __restrict__ offs,
                                                     const int* __restrict__ bsum) {
    __shared__ int pfx_s;
    const int t = threadIdx.x;
    if (t < 64) {
        int v = (t < NSCAN && t < (int)blockIdx.x) ? bsum[t] : 0;
        #pragma unroll
        for (int off = 32; off > 0; off >>= 1) v += __shfl_down(v, off, 64);
        if (t == 0) pfx_s = v;  // sum of bsum[0..blockIdx.x-1]
    }
    __syncthreads();
    const int pfx = pfx_s;
    const int i = blockIdx.x * 1024 + t;
    if (i < N_NODES) offs[i] += pfx;
    if (i == N_NODES) offs[N_NODES] = N_EDGES;
}

// sortscatter: slot = offs[d] + (atomicSub(deg[d]) - 1); payload carries src
// and all 4 edge weights as bf16 (deg is dead after scanA -> reuse as cursor).
__global__ __launch_bounds__(256) void sortscatter_kernel(
        const int* __restrict__ src, const int* __restrict__ dst,
        const float* __restrict__ ew, const int* __restrict__ offs,
        int* __restrict__ deg, int4* __restrict__ sorted_pe) {
    int e = blockIdx.x * 256 + threadIdx.x;
    if (e >= N_EDGES) return;
    const int d = dst[e];
    const int old = atomicSub(&deg[d], 1);
    const float4 w = ((const float4*)ew)[e];
    sorted_pe[offs[d] + old - 1] =
        make_int4(src[e], (int)packbf2(w.x, w.y), (int)packbf2(w.z, w.w), 0);
}

// ---------------------------------------------------------------------------
// Fused: per 16-node tile:
//   phase 1: CSR aggregate. Lanes 0-31 gather edge A's row (uint2 = 4 feats),
//            lanes 32-63 edge B's -> one 512B load per edge PAIR. 4 masked
//            pair-slots in flight (8 edges). Cross-half combine via shfl_xor,
//            bf16 -> XOR-swizzled LDS (layout identical to R7-verified).
//   phase 2: GEMM1 via mfma_f32_16x16x32_bf16 (+bias,relu,channel-sum)
//   phase 3: h tile -> bf16 LDS (same swizzle family)
//   phase 4: GEMM2 via MFMA, + final bias, f32 out
// Swizzle: physical word = logical word ^ ((row&7)<<2)  [32-bit units]
// ---------------------------------------------------------------------------
__global__ __launch_bounds__(256) void fused_kernel(
        const unsigned* __restrict__ nsbf,
        const int* __restrict__ offs,
        const int4* __restrict__ sorted_pe,
        const uint4* __restrict__ wfrag,
        const float* __restrict__ bias,
        const uint4* __restrict__ fwfrag,
        const float* __restrict__ fb,
        float* __restrict__ out) {
    __shared__ unsigned aggU[CH][TM][64];        // bf16 pairs, 16 KB
    __shared__ unsigned short hS[TM][FEAT];      // bf16, 4 KB
    const int t = threadIdx.x;
    const int lane = t & 63;
    const int wid = t >> 6;  // 0..3
    const int row0 = blockIdx.x * TM;
    const int half = lane >> 5;   // 0: edge A, 1: edge B
    const int l31 = lane & 31;    // feats 4*l31 .. 4*l31+3
    const uint2* nsbf2 = (const uint2*)nsbf;

    // ---- phase 1: wave wid aggregates nodes wid*4 .. wid*4+3 ----
    for (int r = 0; r < 4; ++r) {
        const int row = wid * 4 + r;
        const int gn = row0 + row;
        f32x4 A0 = {0.f, 0.f, 0.f, 0.f}, A1 = A0, A2 = A0, A3 = A0;
        const int beg = offs[gn];
        const int end = offs[gn + 1];
        for (int e = beg; e < end; e += 8) {
#define PAIRSLOT(EO) {                                              \
            int ee = (EO) + half;                                   \
            const float m = (ee < end) ? 1.f : 0.f;                 \
            ee = min(ee, end - 1);                                  \
            const int4 pl = sorted_pe[ee];                          \
            const uint2 xr = nsbf2[(unsigned)pl.x * 32u + l31];     \
            const float w0 = bfl((unsigned)pl.y) * m;               \
            const float w1 = bfh((unsigned)pl.y) * m;               \
            const float w2 = bfl((unsigned)pl.z) * m;               \
            const float w3 = bfh((unsigned)pl.z) * m;               \
            const f32x4 xv = {bfl(xr.x), bfh(xr.x), bfl(xr.y), bfh(xr.y)}; \
            A0 += xv * w0; A1 += xv * w1; A2 += xv * w2; A3 += xv * w3; }
            PAIRSLOT(e)
            PAIRSLOT(e + 2)
            PAIRSLOT(e + 4)
            PAIRSLOT(e + 6)
#undef PAIRSLOT
        }
        // combine the two lane-halves (edge A partials + edge B partials)
        #pragma unroll
        for (int q = 0; q < 4; ++q) {
            A0[q] += __shfl_xor(A0[q], 32, 64);
            A1[q] += __shfl_xor(A1[q], 32, 64);
            A2[q] += __shfl_xor(A2[q], 32, 64);
            A3[q] += __shfl_xor(A3[q], 32, 64);
        }
        if (lane < 32) {
            const int widx = (2 * l31) ^ ((row & 7) << 2);  // even; +1 stays adjacent
            *(uint2*)&aggU[0][row][widx] = (uint2){packbf2(A0[0], A0[1]), packbf2(A0[2], A0[3])};
            *(uint2*)&aggU[1][row][widx] = (uint2){packbf2(A1[0], A1[1]), packbf2(A1[2], A1[3])};
            *(uint2*)&aggU[2][row][widx] = (uint2){packbf2(A2[0], A2[1]), packbf2(A2[2], A2[3])};
            *(uint2*)&aggU[3][row][widx] = (uint2){packbf2(A3[0], A3[1]), packbf2(A3[2], A3[3])};
        }
    }
    __syncthreads();

    // ---- phase 2: GEMM1 h = sum_c relu(agg_c @ W_c + b_c) via MFMA ----
    const int arow = lane & 15;
    const int kg4  = (lane >> 4) << 2;   // k-group in words
    const int asw  = (arow & 7) << 2;
    const int ct0  = wid * 2;            // this wave's two 16-col tiles
    const int colA = ct0 * 16 + arow;
    const int colB = colA + 16;

    f32x4 hacc0 = {0.f, 0.f, 0.f, 0.f}, hacc1 = {0.f, 0.f, 0.f, 0.f};
    #pragma unroll
    for (int c = 0; c < CH; ++c) {
        f32x4 acc0 = {0.f, 0.f, 0.f, 0.f}, acc1 = {0.f, 0.f, 0.f, 0.f};
        #pragma unroll
        for (int kt = 0; kt < 4; ++kt) {
            const uint4 au = *(const uint4*)&aggU[c][arow][(kt * 16 + kg4) ^ asw];
            const bf16x8 a  = __builtin_bit_cast(bf16x8, au);
            const bf16x8 b0 = __builtin_bit_cast(bf16x8, wfrag[((c * 4 + kt) * 8 + ct0) * 64 + lane]);
            const bf16x8 b1 = __builtin_bit_cast(bf16x8, wfrag[((c * 4 + kt) * 8 + ct0 + 1) * 64 + lane]);
            acc0 = __builtin_amdgcn_mfma_f32_16x16x32_bf16(a, b0, acc0, 0, 0, 0);
            acc1 = __builtin_amdgcn_mfma_f32_16x16x32_bf16(a, b1, acc1, 0, 0, 0);
        }
        const float bb0 = bias[colA * CH + c];
        const float bb1 = bias[colB * CH + c];
        #pragma unroll
        for (int q = 0; q < 4; ++q) {
            hacc0[q] += fmaxf(acc0[q] + bb0, 0.f);
            hacc1[q] += fmaxf(acc1[q] + bb1, 0.f);
        }
    }

    // ---- phase 3: h tile -> LDS bf16 (C/D: col=lane&15(+16ct), row=(lane>>4)*4+q) ----
    const int rrow0 = (lane >> 4) << 2;
    #pragma unroll
    for (int q = 0; q < 4; ++q) {
        const int row = rrow0 + q;
        const int s8 = (row & 7) << 3;
        hS[row][colA ^ s8] = f2bf(hacc0[q]);
        hS[row][colB ^ s8] = f2bf(hacc1[q]);
    }
    __syncthreads();

    // ---- phase 4: GEMM2 out = h @ fw^T + fb via MFMA ----
    f32x4 o0 = {0.f, 0.f, 0.f, 0.f}, o1 = {0.f, 0.f, 0.f, 0.f};
    const int asw8 = (arow & 7) << 3;
    #pragma unroll
    for (int kt = 0; kt < 4; ++kt) {
        const uint4 hu = *(const uint4*)&hS[arow][(kt * 32 + (kg4 << 1)) ^ asw8];
        const bf16x8 a  = __builtin_bit_cast(bf16x8, hu);
        const bf16x8 b0 = __builtin_bit_cast(bf16x8, fwfrag[(kt * 8 + ct0) * 64 + lane]);
        const bf16x8 b1 = __builtin_bit_cast(bf16x8, fwfrag[(kt * 8 + ct0 + 1) * 64 + lane]);
        o0 = __builtin_amdgcn_mfma_f32_16x16x32_bf16(a, b0, o0, 0, 0, 0);
        o1 = __builtin_amdgcn_mfma_f32_16x16x32_bf16(a, b1, o1, 0, 0, 0);
    }
    const float fb0 = fb[colA];
    const float fb1 = fb[colB];
    #pragma unroll
    for (int q = 0; q < 4; ++q) {
        const int gr = row0 + rrow0 + q;
        out[gr * FEAT + colA] = o0[q] + fb0;
        out[gr * FEAT + colB] = o1[q] + fb1;
    }
}

// ---------------------------------------------------------------------------
extern "C" void kernel_launch(void* const* d_in, const int* in_sizes, int n_in,
                              void* d_out, int out_size, void* d_ws, size_t ws_size,
                              hipStream_t stream) {
    const float* node_state = (const float*)d_in[0];
    const float* edge_w     = (const float*)d_in[1];
    const float* weight     = (const float*)d_in[2];
    const float* bias       = (const float*)d_in[3];
    const float* final_w    = (const float*)d_in[4];
    const float* final_b    = (const float*)d_in[5];
    const int*   src        = (const int*)d_in[6];
    const int*   dst        = (const int*)d_in[7];
    float* out = (float*)d_out;

    // Workspace layout (16B-aligned chunks):
    char* ws = (char*)d_ws;
    int*      deg       = (int*)(ws + 0);             // 200,000 B
    int*      offs      = (int*)(ws + 200064);        // 200,004 B (50001 ints)
    int*      bsum      = (int*)(ws + 400192);        // 196 B
    int4*     sorted_pe = (int4*)(ws + 400448);       // 12.8 MB
    unsigned* nsbf      = (unsigned*)(ws + 13200448); // 12.8 MB
    uint4*    wfrag     = (uint4*)(ws + 26000448);    // 131,072 B
    uint4*    fwfrag    = (uint4*)(ws + 26131520);    // 32,768 B
    // total ~26.2 MB

    const int prep_total = RANGE_A + RANGE_B + RANGE_C;
    pack_all_kernel<<<(prep_total + 255) / 256, 256, 0, stream>>>(
        node_state, weight, final_w, nsbf, wfrag, fwfrag, deg);

    hist_kernel<<<(N_EDGES + 255) / 256, 256, 0, stream>>>(dst, deg);
    scanA_kernel<<<NSCAN, 1024, 0, stream>>>(deg, offs, bsum);
    scanB_kernel<<<NSCAN, 1024, 0, stream>>>(offs, bsum);
    sortscatter_kernel<<<(N_EDGES + 255) / 256, 256, 0, stream>>>(
        src, dst, edge_w, offs, deg, sorted_pe);

    fused_kernel<<<N_NODES / TM, 256, 0, stream>>>(
        nsbf, offs, sorted_pe, wfrag, bias, fwfrag, final_b, out);
}